// Round 8
// baseline (481.542 us; speedup 1.0000x reference)
//
#include <hip/hip_runtime.h>
#include <hip/hip_bf16.h>

// ---------------------------------------------------------------------------
// AttentionBase: out = softmax((in@Wq^T+bq)*ds @ (mem@Wk^T+bk)^T) @ (mem@Wv^T+bv) @ Wo^T + bo
// B=8, S=2048, C=1024. All matmuls bf16 MFMA gemm_bt.
// Skeleton: 128x128 tile, 256 thr (4 waves 2x2), BK=32 TRIPLE-buffered LDS
// (48 KB -> 3 blocks/CU; inter-block overlap is the latency-hiding engine,
// m97/m114 evidence), depth-2 prefetch, counted vmcnt(4) (never 0 in steady
// state), granule swizzle both-sides -> 0 bank conflicts, T1 XCD swizzle,
// setprio(1) around the MFMA cluster.
// PV row-sums via ones-operand MFMA. d_out doubles as scratch (Vt | inb).
// ---------------------------------------------------------------------------

typedef __attribute__((ext_vector_type(8))) short short8;   // 8 bf16 = 4 VGPRs
typedef __attribute__((ext_vector_type(4))) float f32x4;

static __device__ __forceinline__ unsigned short f2bf(float f) {
  union { float f; unsigned u; } x; x.f = f;
  unsigned r = x.u + 0x7FFFu + ((x.u >> 16) & 1u);   // round-to-nearest-even
  return (unsigned short)(r >> 16);
}

static __device__ __forceinline__ void g2l16(const void* g, void* l) {
  __builtin_amdgcn_global_load_lds(
      (const __attribute__((address_space(1))) void*)g,
      (__attribute__((address_space(3))) void*)l, 16, 0, 0);
}

template <int N> static __device__ __forceinline__ void vmw() {
  if constexpr (N == 4)      asm volatile("s_waitcnt vmcnt(4)" ::: "memory");
  else                       asm volatile("s_waitcnt vmcnt(0)" ::: "memory");
}

// f32 -> bf16: input & memory in one launch (blockIdx.y selects)
__global__ __launch_bounds__(256) void cvt2_kernel(const float* __restrict__ s0,
                                                   const float* __restrict__ s1,
                                                   unsigned short* __restrict__ o0,
                                                   unsigned short* __restrict__ o1,
                                                   long long n4) {
  const float* src = blockIdx.y ? s1 : s0;
  unsigned short* dst = blockIdx.y ? o1 : o0;
  long long i = (long long)blockIdx.x * 256 + threadIdx.x;
  const long long stride = (long long)gridDim.x * 256;
  for (; i < n4; i += stride) {
    float4 v = ((const float4*)src)[i];
    ushort4 o;
    o.x = f2bf(v.x); o.y = f2bf(v.y); o.z = f2bf(v.z); o.w = f2bf(v.w);
    ((ushort4*)dst)[i] = o;
  }
}

// all four C*C weights in one launch; blockIdx.y selects the matrix
__global__ __launch_bounds__(256) void wcvt_kernel(
    const float* __restrict__ w0, const float* __restrict__ w1,
    const float* __restrict__ w2, const float* __restrict__ w3,
    unsigned short* __restrict__ o0, unsigned short* __restrict__ o1,
    unsigned short* __restrict__ o2, unsigned short* __restrict__ o3,
    int n4) {
  const float* src; unsigned short* dst;
  switch (blockIdx.y) {
    case 0: src = w0; dst = o0; break;
    case 1: src = w1; dst = o1; break;
    case 2: src = w2; dst = o2; break;
    default: src = w3; dst = o3; break;
  }
  int i = blockIdx.x * 256 + threadIdx.x;
  const int stride = gridDim.x * 256;
  for (; i < n4; i += stride) {
    float4 v = ((const float4*)src)[i];
    ushort4 o;
    o.x = f2bf(v.x); o.y = f2bf(v.y); o.z = f2bf(v.z); o.w = f2bf(v.w);
    ((ushort4*)dst)[i] = o;
  }
}

#define EPI_BF16 0
#define EPI_BF16_TRANS 1
#define EPI_EXP 2
#define EPI_PV 3
#define EPI_F32 4

// D[m][n] = epilogue(sum_k A[m][k]*B[n][k] (+bias[n]) (*scale)), batched via z.
// 128x128 tile, 256 threads, 4 waves 2x2, BK=32, triple-buffered.
template <int EPI, bool HAS_BIAS>
__global__ __launch_bounds__(256, 3) void gemm_kernel(
    const unsigned short* __restrict__ A, const unsigned short* __restrict__ B,
    const float* __restrict__ bias, void* __restrict__ Dv,
    int K, int lda, int ldb, int ldd,
    long long sA, long long sB, long long sD, float scale) {
  constexpr int SL = 128 * 32;          // slice elements (A or B)

  // ---- T1: chunked XCD swizzle over the flattened grid (nwg % 8 == 0) ----
  int lin = blockIdx.x + gridDim.x * (blockIdx.y + gridDim.y * blockIdx.z);
  const int nwg = gridDim.x * gridDim.y * gridDim.z;
  lin = (lin & 7) * (nwg >> 3) + (lin >> 3);
  const int bx = lin % gridDim.x;
  int rem0 = lin / gridDim.x;
  const int by = rem0 % gridDim.y;
  const int bz = rem0 / gridDim.y;

  const int bm = bx * 128;
  const int bn = by * 128;
  const int tid = threadIdx.x;
  const int lane = tid & 63;
  const int wid = tid >> 6;
  const int wr = (wid >> 1) * 64;      // wave row offset
  const int wc = (wid & 1) * 64;       // wave col offset
  const int fr = lane & 15;
  const int hi = lane >> 4;
  const int rg = ((hi ^ ((fr >> 1) & 3)) << 3);   // swizzled read granule (elems)

  __shared__ __align__(16) unsigned short As[3 * SL];
  __shared__ __align__(16) unsigned short Bs[3 * SL];

  f32x4 acc[4][4];
#pragma unroll
  for (int m = 0; m < 4; ++m)
#pragma unroll
    for (int n = 0; n < 4; ++n) acc[m][n] = (f32x4){0.f, 0.f, 0.f, 0.f};

  f32x4 asum[4];          // PV: row-sums via ones-operand MFMA
  short8 ones;
#pragma unroll
  for (int m = 0; m < 4; ++m) asum[m] = (f32x4){0.f, 0.f, 0.f, 0.f};
#pragma unroll
  for (int j = 0; j < 8; ++j) ones[j] = (short)0x3F80;  // bf16 1.0

  // ---- stage pointers: slot = i*256+tid (i=0,1), row = slot>>2,
  //      source granule XOR-permuted (both-sides swizzle) ----
  const unsigned short* apt[2];
  const unsigned short* bpt[2];
#pragma unroll
  for (int i = 0; i < 2; ++i) {
    const int slot = i * 256 + tid;
    const int row = slot >> 2;
    const int g = (slot & 3) ^ ((row >> 1) & 3);
    apt[i] = A + (long long)bz * sA + (long long)(bm + row) * lda + g * 8;
    bpt[i] = B + (long long)bz * sB + (long long)(bn + row) * ldb + g * 8;
  }
  // stage slice tt into buf: 2 A-issues + 2 B-issues, pointers advance +32
  auto stage = [&](int buf) {
#pragma unroll
    for (int i = 0; i < 2; ++i) {
      g2l16(apt[i], &As[buf * SL + (i * 256 + tid) * 8]);
      apt[i] += 32;
    }
#pragma unroll
    for (int i = 0; i < 2; ++i) {
      g2l16(bpt[i], &Bs[buf * SL + (i * 256 + tid) * 8]);
      bpt[i] += 32;
    }
  };

  const int NT = K >> 5;   // K-slices of 32

  // ---- prologue: fill pipeline 2 slices deep, sync slice 0 ----
  stage(0);
  stage(1);
  vmw<4>();                            // slice 0 landed, slice 1 in flight
  __builtin_amdgcn_s_barrier();
  __builtin_amdgcn_sched_barrier(0);

  for (int t = 0; t < NT; ++t) {
    const int buf = t % 3;
    if (t + 2 < NT) stage((t + 2) % 3);   // buffer freed at t-1's barrier

    short8 af[4], bf[4];
#pragma unroll
    for (int m = 0; m < 4; ++m)
      af[m] = *(const short8*)&As[buf * SL + (wr + m * 16 + fr) * 32 + rg];
#pragma unroll
    for (int n = 0; n < 4; ++n)
      bf[n] = *(const short8*)&Bs[buf * SL + (wc + n * 16 + fr) * 32 + rg];
    __builtin_amdgcn_s_setprio(1);
#pragma unroll
    for (int m = 0; m < 4; ++m)
#pragma unroll
      for (int n = 0; n < 4; ++n)
        acc[m][n] = __builtin_amdgcn_mfma_f32_16x16x32_bf16(af[m], bf[n],
                                                            acc[m][n], 0, 0, 0);
    if (EPI == EPI_PV) {
#pragma unroll
      for (int m = 0; m < 4; ++m)
        asum[m] = __builtin_amdgcn_mfma_f32_16x16x32_bf16(af[m], ones,
                                                          asum[m], 0, 0, 0);
    }
    __builtin_amdgcn_s_setprio(0);
    __builtin_amdgcn_sched_barrier(0);
    // slice t+1 must be resident before next iteration's ds_reads
    if (t + 2 < NT)      vmw<4>();     // drain t+1, keep t+2 in flight
    else if (t + 1 < NT) vmw<0>();     // tail
    __builtin_amdgcn_s_barrier();
    __builtin_amdgcn_sched_barrier(0);
  }

  // ---- epilogue: C/D frag layout col=lane&15, row=(lane>>4)*4+j ----
  const int cr = hi * 4;
  const int cc = fr;
#pragma unroll
  for (int m = 0; m < 4; ++m) {
    const int row0 = bm + wr + m * 16 + cr;
#pragma unroll
    for (int n = 0; n < 4; ++n) {
      const int col = bn + wc + n * 16 + cc;
      const float bv = HAS_BIAS ? bias[col] : 0.f;
      if (EPI == EPI_F32) {
        float* D = (float*)Dv + (long long)bz * sD;
#pragma unroll
        for (int j = 0; j < 4; ++j)
          D[(long long)(row0 + j) * ldd + col] = acc[m][n][j] + bv;
      } else if (EPI == EPI_BF16) {
        unsigned short* D = (unsigned short*)Dv + (long long)bz * sD;
#pragma unroll
        for (int j = 0; j < 4; ++j)
          D[(long long)(row0 + j) * ldd + col] = f2bf((acc[m][n][j] + bv) * scale);
      } else if (EPI == EPI_BF16_TRANS) {
        unsigned short* D = (unsigned short*)Dv + (long long)bz * sD;
        ushort4 pk;
        pk.x = f2bf((acc[m][n][0] + bv) * scale);
        pk.y = f2bf((acc[m][n][1] + bv) * scale);
        pk.z = f2bf((acc[m][n][2] + bv) * scale);
        pk.w = f2bf((acc[m][n][3] + bv) * scale);
        *(ushort4*)&D[(long long)col * ldd + row0] = pk;
      } else if (EPI == EPI_EXP) {
        unsigned short* D = (unsigned short*)Dv + (long long)bz * sD;
#pragma unroll
        for (int j = 0; j < 4; ++j)
          D[(long long)(row0 + j) * ldd + col] = f2bf(__expf(acc[m][n][j]));
      } else {  // EPI_PV: normalize by MFMA-computed row-sum
        unsigned short* D = (unsigned short*)Dv + (long long)bz * sD;
#pragma unroll
        for (int j = 0; j < 4; ++j) {
          const float li = 1.f / asum[m][j];
          D[(long long)(row0 + j) * ldd + col] = f2bf(acc[m][n][j] * li);
        }
      }
    }
  }
}

extern "C" void kernel_launch(void* const* d_in, const int* in_sizes, int n_in,
                              void* d_out, int out_size, void* d_ws, size_t ws_size,
                              hipStream_t stream) {
  (void)in_sizes; (void)n_in; (void)out_size;
  const float* input  = (const float*)d_in[0];
  const float* memory = (const float*)d_in[1];
  const float* Wq = (const float*)d_in[2];
  const float* bq = (const float*)d_in[3];
  const float* Wk = (const float*)d_in[4];
  const float* bk = (const float*)d_in[5];
  const float* Wv = (const float*)d_in[6];
  const float* bv = (const float*)d_in[7];
  const float* Wo = (const float*)d_in[8];
  const float* bo = (const float*)d_in[9];
  float* out = (float*)d_out;

  const int S = 2048, C = 1024;
  const int CB = 4;                                // batches per attention chunk
  const long long BS = 16384;                      // 8 * 2048
  const long long N_IN = BS * C;                   // 16,777,216
  const long long N_W  = (long long)C * C;         // 1,048,576

  // ---- workspace layout (256B aligned), ~109 MiB ----
  char* p = (char*)d_ws;
  auto alloc = [&](size_t bytes) {
    char* r = p;
    p += (bytes + 255) & ~(size_t)255;
    return r;
  };
  unsigned short* wqb  = (unsigned short*)alloc(N_W * 2);
  unsigned short* wkb  = (unsigned short*)alloc(N_W * 2);
  unsigned short* wvb  = (unsigned short*)alloc(N_W * 2);
  unsigned short* wob  = (unsigned short*)alloc(N_W * 2);
  unsigned short* Qb   = (unsigned short*)alloc(N_IN * 2);   // [16384][1024]; later sel
  unsigned short* Kb   = (unsigned short*)alloc(N_IN * 2);   // [16384][1024]
  unsigned short* Xb   = (unsigned short*)alloc(N_IN * 2);   // memb, then Pt
  if ((size_t)(p - (char*)d_ws) > ws_size) return;

  // d_out scratch: [Vt bf16 16M | inb bf16 16M] = exactly 64 MiB
  unsigned short* Vt  = (unsigned short*)d_out;          // [1024][16384]
  unsigned short* inb = (unsigned short*)d_out + N_IN;   // [16384][1024]
  unsigned short* memb = Xb;
  unsigned short* Pt   = Xb;                             // alias after memb dead

  // ---- f32 -> bf16 ----
  wcvt_kernel<<<dim3(256, 4, 1), 256, 0, stream>>>(Wq, Wk, Wv, Wo,
                                                   wqb, wkb, wvb, wob,
                                                   (int)(N_W / 4));
  cvt2_kernel<<<dim3(2048, 2, 1), 256, 0, stream>>>(memory, input, memb, inb,
                                                    N_IN / 4);

  const float depth_scale = 0.03125f;  // 1024^-0.5

  // ---- projections: 128x128 tile, grid 1024 blocks (4/CU peak) ----
  gemm_kernel<EPI_BF16, true><<<dim3(128, 8, 1), 256, 0, stream>>>(
      memb, wkb, bk, Kb, C, C, C, C, 0, 0, 0, 1.0f);
  gemm_kernel<EPI_BF16_TRANS, true><<<dim3(128, 8, 1), 256, 0, stream>>>(
      memb, wvb, bv, Vt, C, C, C, (int)BS, 0, 0, 0, 1.0f);
  gemm_kernel<EPI_BF16, true><<<dim3(128, 8, 1), 256, 0, stream>>>(
      inb, wqb, bq, Qb, C, C, C, C, 0, 0, 0, depth_scale);

  // ---- attention, CB=4 batches at a time (memb dead -> Pt) ----
  for (int c = 0; c < 8 / CB; ++c) {
    const long long qoff = (long long)c * CB * S * C;
    // P~ = exp(Q[b] @ K[b]^T) -> bf16 [CB*2048][2048], grid (16,16,4)=1024
    gemm_kernel<EPI_EXP, false><<<dim3(16, 16, CB), 256, 0, stream>>>(
        Qb + qoff, Kb + qoff, nullptr, Pt,
        C, C, C, S, (long long)S * C, (long long)S * C, (long long)S * S, 1.0f);
    // sel[b] = (P~ @ V[b]) / rowsum(P~) -> bf16 over dead Q rows, grid (16,8,4)=512
    gemm_kernel<EPI_PV, false><<<dim3(16, 8, CB), 256, 0, stream>>>(
        Pt, Vt + (long long)c * CB * S, nullptr, Qb + qoff,
        S, S, (int)BS, C, (long long)S * S, (long long)S, (long long)S * C, 1.0f);
  }

  // ---- out = sel @ Wo^T + bo -> f32 d_out (overwrites Vt/inb scratch) ----
  gemm_kernel<EPI_F32, true><<<dim3(128, 8, 1), 256, 0, stream>>>(
      Qb, wob, bo, out, C, C, C, C, 0, 0, 0, 1.0f);
}

// Round 9
// 469.783 us; speedup vs baseline: 1.0250x; 1.0250x over previous
//
#include <hip/hip_runtime.h>
#include <hip/hip_bf16.h>

// ---------------------------------------------------------------------------
// AttentionBase: out = softmax((in@Wq^T+bq)*ds @ (mem@Wk^T+bk)^T) @ (mem@Wv^T+bv) @ Wo^T + bo
// B=8, S=2048, C=1024. All matmuls bf16 MFMA gemm_bt on a BRICK layout:
// every operand is pre-packed (by the cvt kernels and by every GEMM epilogue)
// into the exact LDS slice image: per 128-row tile, per 32-k slice, element
// (r,k) lives at  r*32 + ((g ^ ((r>>1)&3))<<3) + (k&7), g=(k>>3)&3  — i.e.
// the granule swizzle is baked into the file. GEMM staging is then
// global_load_lds of CONTIGUOUS 16B/lane (1 KB/wave, full 128B lines, no
// address math) and ds_reads use the same xor -> 0 bank conflicts.
// Skeleton: r8 (128x128 tile, 4 waves, BK=32 triple-buffer, counted vmcnt(4),
// T1 XCD swizzle, setprio, PV row-sums via ones-MFMA, d_out as scratch).
// ---------------------------------------------------------------------------

typedef __attribute__((ext_vector_type(8))) short short8;   // 8 bf16 = 4 VGPRs
typedef __attribute__((ext_vector_type(4))) float f32x4;

static __device__ __forceinline__ unsigned short f2bf(float f) {
  union { float f; unsigned u; } x; x.f = f;
  unsigned r = x.u + 0x7FFFu + ((x.u >> 16) & 1u);   // round-to-nearest-even
  return (unsigned short)(r >> 16);
}

static __device__ __forceinline__ void g2l16(const void* g, void* l) {
  __builtin_amdgcn_global_load_lds(
      (const __attribute__((address_space(1))) void*)g,
      (__attribute__((address_space(3))) void*)l, 16, 0, 0);
}

template <int N> static __device__ __forceinline__ void vmw() {
  if constexpr (N == 4) asm volatile("s_waitcnt vmcnt(4)" ::: "memory");
  else                  asm volatile("s_waitcnt vmcnt(0)" ::: "memory");
}

// brick element offset for element (row r_, k k_) in a brick file of depth Kd
static __device__ __forceinline__ long long brickoff(int r_, int k_, int Kd) {
  return (long long)(r_ >> 7) * ((long long)128 * Kd) +
         (long long)(k_ >> 5) * 4096 +
         (r_ & 127) * 32 +
         (((((k_ >> 3) & 3) ^ ((r_ >> 1) & 3))) << 3) +
         (k_ & 7);
}

// f32 row-major [M][1024] -> bf16 bricks (Kd=1024); two tensors per launch.
__global__ __launch_bounds__(256) void cvt_brick_kernel(
    const float* __restrict__ s0, const float* __restrict__ s1,
    unsigned short* __restrict__ o0, unsigned short* __restrict__ o1,
    long long ngran) {
  const float* src = blockIdx.y ? s1 : s0;
  unsigned short* dst = blockIdx.y ? o1 : o0;
  long long gid = (long long)blockIdx.x * 256 + threadIdx.x;
  const long long stride = (long long)gridDim.x * 256;
  for (; gid < ngran; gid += stride) {
    // decode brick position -> source (row, k) with Kd = 1024
    const int tile = (int)(gid >> 14);          // 16384 granules per 128x1024 tile
    const int g2 = (int)(gid & 16383);
    const int ks = g2 >> 9;                     // k-slice
    const int rp = g2 & 511;
    const int r = rp >> 2;                      // row in tile
    const int p = rp & 3;                       // stored granule position
    const int g = p ^ ((r >> 1) & 3);           // source logical granule
    const float* sp = src + (long long)(tile * 128 + r) * 1024 + ks * 32 + g * 8;
    float4 u0 = ((const float4*)sp)[0];
    float4 u1 = ((const float4*)sp)[1];
    short8 pk;
    pk[0] = (short)f2bf(u0.x); pk[1] = (short)f2bf(u0.y);
    pk[2] = (short)f2bf(u0.z); pk[3] = (short)f2bf(u0.w);
    pk[4] = (short)f2bf(u1.x); pk[5] = (short)f2bf(u1.y);
    pk[6] = (short)f2bf(u1.z); pk[7] = (short)f2bf(u1.w);
    *(short8*)&dst[gid * 8] = pk;
  }
}

// all four C*C weights f32 -> bricks in one launch (blockIdx.y selects)
__global__ __launch_bounds__(256) void wcvt_brick_kernel(
    const float* __restrict__ w0, const float* __restrict__ w1,
    const float* __restrict__ w2, const float* __restrict__ w3,
    unsigned short* __restrict__ o0, unsigned short* __restrict__ o1,
    unsigned short* __restrict__ o2, unsigned short* __restrict__ o3) {
  const float* src; unsigned short* dst;
  switch (blockIdx.y) {
    case 0: src = w0; dst = o0; break;
    case 1: src = w1; dst = o1; break;
    case 2: src = w2; dst = o2; break;
    default: src = w3; dst = o3; break;
  }
  const int gid = blockIdx.x * 256 + threadIdx.x;   // 512 blocks * 256 = 131072 exact
  const int tile = gid >> 14;
  const int g2 = gid & 16383;
  const int ks = g2 >> 9;
  const int rp = g2 & 511;
  const int r = rp >> 2;
  const int p = rp & 3;
  const int g = p ^ ((r >> 1) & 3);
  const float* sp = src + (long long)(tile * 128 + r) * 1024 + ks * 32 + g * 8;
  float4 u0 = ((const float4*)sp)[0];
  float4 u1 = ((const float4*)sp)[1];
  short8 pk;
  pk[0] = (short)f2bf(u0.x); pk[1] = (short)f2bf(u0.y);
  pk[2] = (short)f2bf(u0.z); pk[3] = (short)f2bf(u0.w);
  pk[4] = (short)f2bf(u1.x); pk[5] = (short)f2bf(u1.y);
  pk[6] = (short)f2bf(u1.z); pk[7] = (short)f2bf(u1.w);
  *(short8*)&dst[(long long)gid * 8] = pk;
}

#define EPI_BF16 0        // brick write, Kd = ldd
#define EPI_BF16_TRANS 1  // brick write transposed (Vt), Kd = ldd
#define EPI_EXP 2         // brick write exp(acc), Kd = ldd
#define EPI_PV 3          // brick write acc/rowsum, Kd = ldd
#define EPI_F32 4         // row-major f32, ld = ldd

// D = epilogue(A x B^T (+bias)(*scale)); A,B are BRICK files.
// ldaK/ldbK: brick K-depth of A/B. sA: A flat batch elem offset. sBflat: B flat
// batch offset. sBslice: per-z B k-slice offset. kOffB: constant B k-slice off.
// sD: dest flat batch elem offset. NT: K/32 slices.
template <int EPI, bool HAS_BIAS>
__global__ __launch_bounds__(256, 3) void gemm_kernel(
    const unsigned short* __restrict__ A, const unsigned short* __restrict__ B,
    const float* __restrict__ bias, void* __restrict__ Dv,
    int NT, int ldaK, int ldbK, int ldd,
    long long sA, long long sBflat, int sBslice, int kOffB,
    long long sD, float scale) {
  constexpr int SL = 4096;   // slice elems

  // ---- T1: chunked XCD swizzle over the flattened grid (nwg % 8 == 0) ----
  int lin = blockIdx.x + gridDim.x * (blockIdx.y + gridDim.y * blockIdx.z);
  const int nwg = gridDim.x * gridDim.y * gridDim.z;
  lin = (lin & 7) * (nwg >> 3) + (lin >> 3);
  const int bx = lin % gridDim.x;
  int rem0 = lin / gridDim.x;
  const int by = rem0 % gridDim.y;
  const int bz = rem0 / gridDim.y;

  const int bm = bx * 128;
  const int bn = by * 128;
  const int tid = threadIdx.x;
  const int lane = tid & 63;
  const int wid = tid >> 6;
  const int wr = (wid >> 1) * 64;
  const int wc = (wid & 1) * 64;
  const int fr = lane & 15;
  const int hi = lane >> 4;
  const int rg = ((hi ^ ((fr >> 1) & 3)) << 3);   // swizzled read granule

  __shared__ __align__(16) unsigned short As[3 * SL];
  __shared__ __align__(16) unsigned short Bs[3 * SL];

  f32x4 acc[4][4];
#pragma unroll
  for (int m = 0; m < 4; ++m)
#pragma unroll
    for (int n = 0; n < 4; ++n) acc[m][n] = (f32x4){0.f, 0.f, 0.f, 0.f};

  f32x4 asum[4];
  short8 ones;
#pragma unroll
  for (int m = 0; m < 4; ++m) asum[m] = (f32x4){0.f, 0.f, 0.f, 0.f};
#pragma unroll
  for (int j = 0; j < 8; ++j) ones[j] = (short)0x3F80;  // bf16 1.0

  // ---- brick staging bases: fully contiguous, slot*16B per thread ----
  const unsigned short* Ab = A + bz * sA + (long long)(bm >> 7) * 128 * ldaK;
  const unsigned short* Bb = B + bz * sBflat + (long long)(bn >> 7) * 128 * ldbK +
                             (long long)(kOffB + bz * sBslice) * SL;
  auto stage = [&](int t, int buf) {
    const unsigned short* as = Ab + (long long)t * SL;
    const unsigned short* bs = Bb + (long long)t * SL;
#pragma unroll
    for (int i = 0; i < 2; ++i)
      g2l16(as + (i * 256 + tid) * 8, &As[buf * SL + (i * 256 + tid) * 8]);
#pragma unroll
    for (int i = 0; i < 2; ++i)
      g2l16(bs + (i * 256 + tid) * 8, &Bs[buf * SL + (i * 256 + tid) * 8]);
  };

  // ---- prologue: 2 slices deep, sync slice 0 ----
  stage(0, 0);
  stage(1, 1);
  vmw<4>();
  __builtin_amdgcn_s_barrier();
  __builtin_amdgcn_sched_barrier(0);

  for (int t = 0; t < NT; ++t) {
    const int buf = t % 3;
    if (t + 2 < NT) stage(t + 2, (t + 2) % 3);

    short8 af[4], bf[4];
#pragma unroll
    for (int m = 0; m < 4; ++m)
      af[m] = *(const short8*)&As[buf * SL + (wr + m * 16 + fr) * 32 + rg];
#pragma unroll
    for (int n = 0; n < 4; ++n)
      bf[n] = *(const short8*)&Bs[buf * SL + (wc + n * 16 + fr) * 32 + rg];
    __builtin_amdgcn_s_setprio(1);
#pragma unroll
    for (int m = 0; m < 4; ++m)
#pragma unroll
      for (int n = 0; n < 4; ++n)
        acc[m][n] = __builtin_amdgcn_mfma_f32_16x16x32_bf16(af[m], bf[n],
                                                            acc[m][n], 0, 0, 0);
    if (EPI == EPI_PV) {
#pragma unroll
      for (int m = 0; m < 4; ++m)
        asum[m] = __builtin_amdgcn_mfma_f32_16x16x32_bf16(af[m], ones,
                                                          asum[m], 0, 0, 0);
    }
    __builtin_amdgcn_s_setprio(0);
    __builtin_amdgcn_sched_barrier(0);
    if (t + 2 < NT)      vmw<4>();
    else if (t + 1 < NT) vmw<0>();
    __builtin_amdgcn_s_barrier();
    __builtin_amdgcn_sched_barrier(0);
  }

  // ---- epilogue: C/D frag layout col=lane&15, row=(lane>>4)*4+j ----
  const int cr = hi * 4;
  const int cc = fr;
#pragma unroll
  for (int m = 0; m < 4; ++m) {
    const int row0 = bm + wr + m * 16 + cr;
#pragma unroll
    for (int n = 0; n < 4; ++n) {
      const int col = bn + wc + n * 16 + cc;
      const float bv = HAS_BIAS ? bias[col] : 0.f;
      if (EPI == EPI_F32) {
        float* D = (float*)Dv + bz * sD;
#pragma unroll
        for (int j = 0; j < 4; ++j)
          D[(long long)(row0 + j) * ldd + col] = acc[m][n][j] + bv;
      } else if (EPI == EPI_BF16) {
        unsigned short* D = (unsigned short*)Dv + bz * sD;
#pragma unroll
        for (int j = 0; j < 4; ++j)
          D[brickoff(row0 + j, col, ldd)] = f2bf((acc[m][n][j] + bv) * scale);
      } else if (EPI == EPI_BF16_TRANS) {
        unsigned short* D = (unsigned short*)Dv + bz * sD;
#pragma unroll
        for (int j = 0; j < 4; ++j)
          D[brickoff(col, row0 + j, ldd)] = f2bf((acc[m][n][j] + bv) * scale);
      } else if (EPI == EPI_EXP) {
        unsigned short* D = (unsigned short*)Dv + bz * sD;
#pragma unroll
        for (int j = 0; j < 4; ++j)
          D[brickoff(row0 + j, col, ldd)] = f2bf(__expf(acc[m][n][j]));
      } else {  // EPI_PV
        unsigned short* D = (unsigned short*)Dv + bz * sD;
#pragma unroll
        for (int j = 0; j < 4; ++j) {
          const float li = 1.f / asum[m][j];
          D[brickoff(row0 + j, col, ldd)] = f2bf(acc[m][n][j] * li);
        }
      }
    }
  }
}

extern "C" void kernel_launch(void* const* d_in, const int* in_sizes, int n_in,
                              void* d_out, int out_size, void* d_ws, size_t ws_size,
                              hipStream_t stream) {
  (void)in_sizes; (void)n_in; (void)out_size;
  const float* input  = (const float*)d_in[0];
  const float* memory = (const float*)d_in[1];
  const float* Wq = (const float*)d_in[2];
  const float* bq = (const float*)d_in[3];
  const float* Wk = (const float*)d_in[4];
  const float* bk = (const float*)d_in[5];
  const float* Wv = (const float*)d_in[6];
  const float* bv = (const float*)d_in[7];
  const float* Wo = (const float*)d_in[8];
  const float* bo = (const float*)d_in[9];
  float* out = (float*)d_out;

  const int S = 2048, C = 1024;
  const int CB = 4;
  const long long BS = 16384;
  const long long N_IN = BS * C;        // 16,777,216
  const long long N_W  = (long long)C * C;

  char* p = (char*)d_ws;
  auto alloc = [&](size_t bytes) {
    char* r = p;
    p += (bytes + 255) & ~(size_t)255;
    return r;
  };
  unsigned short* wqb  = (unsigned short*)alloc(N_W * 2);
  unsigned short* wkb  = (unsigned short*)alloc(N_W * 2);
  unsigned short* wvb  = (unsigned short*)alloc(N_W * 2);
  unsigned short* wob  = (unsigned short*)alloc(N_W * 2);
  unsigned short* Qb   = (unsigned short*)alloc(N_IN * 2);   // bricks Kd=1024; later sel
  unsigned short* Kb   = (unsigned short*)alloc(N_IN * 2);   // bricks Kd=1024
  unsigned short* Xb   = (unsigned short*)alloc(N_IN * 2);   // memb bricks, then Pt
  if ((size_t)(p - (char*)d_ws) > ws_size) return;

  unsigned short* Vt  = (unsigned short*)d_out;          // V bricks [8 c-tiles][Kd=16384]
  unsigned short* inb = (unsigned short*)d_out + N_IN;   // input bricks Kd=1024
  unsigned short* memb = Xb;
  unsigned short* Pt   = Xb;                             // P~ bricks Kd=2048 (CB batches)

  // ---- f32 -> bf16 bricks ----
  wcvt_brick_kernel<<<dim3(512, 4, 1), 256, 0, stream>>>(Wq, Wk, Wv, Wo,
                                                         wqb, wkb, wvb, wob);
  cvt_brick_kernel<<<dim3(2048, 2, 1), 256, 0, stream>>>(memory, input, memb, inb,
                                                         N_IN / 8);

  const float depth_scale = 0.03125f;  // 1024^-0.5

  // ---- projections (NT=32): grid (128,8)=1024 blocks ----
  // K = mem @ Wk^T + bk -> Kb bricks
  gemm_kernel<EPI_BF16, true><<<dim3(128, 8, 1), 256, 0, stream>>>(
      memb, wkb, bk, Kb, 32, C, C, C, 0, 0, 0, 0, 0, 1.0f);
  // Vt = (mem @ Wv^T + bv)^T -> V B-bricks (rows=c, Kd=16384)
  gemm_kernel<EPI_BF16_TRANS, true><<<dim3(128, 8, 1), 256, 0, stream>>>(
      memb, wvb, bv, Vt, 32, C, C, (int)BS, 0, 0, 0, 0, 0, 1.0f);
  // Q = (in @ Wq^T + bq) * ds -> Qb bricks
  gemm_kernel<EPI_BF16, true><<<dim3(128, 8, 1), 256, 0, stream>>>(
      inb, wqb, bq, Qb, 32, C, C, C, 0, 0, 0, 0, 0, depth_scale);

  // ---- attention, CB=4 batches per chunk (memb dead -> Pt) ----
  for (int c = 0; c < 8 / CB; ++c) {
    const long long qoff = (long long)c * CB * S * C;
    // P~ = exp(Q[b] @ K[b]^T) -> Pt bricks Kd=2048; grid (16,16,4)=1024
    gemm_kernel<EPI_EXP, false><<<dim3(16, 16, CB), 256, 0, stream>>>(
        Qb + qoff, Kb + qoff, nullptr, Pt,
        32, C, C, S, (long long)S * C, (long long)S * C, 0, 0,
        (long long)S * S, 1.0f);
    // sel[b] = (P~ @ V[b]) / rowsum -> sel bricks over dead Q rows; grid (16,8,4)=512
    // B = Vt bricks Kd=16384 with k-slice offset (c*CB + bz)*64
    gemm_kernel<EPI_PV, false><<<dim3(16, 8, CB), 256, 0, stream>>>(
        Pt, Vt, nullptr, Qb + qoff,
        64, S, (int)BS, C, (long long)S * S, 0, 64, c * CB * 64,
        (long long)S * C, 1.0f);
  }

  // ---- out = sel @ Wo^T + bo -> f32 row-major d_out ----
  gemm_kernel<EPI_F32, true><<<dim3(128, 8, 1), 256, 0, stream>>>(
      Qb, wob, bo, out, 32, C, C, C, 0, 0, 0, 0, 0, 1.0f);
}

// Round 10
// 396.046 us; speedup vs baseline: 1.2159x; 1.1862x over previous
//
#include <hip/hip_runtime.h>
#include <hip/hip_bf16.h>

// ---------------------------------------------------------------------------
// AttentionBase: out = softmax((in@Wq^T+bq)*ds @ (mem@Wk^T+bk)^T) @ (mem@Wv^T+bv) @ Wo^T + bo
// B=8, S=2048, C=1024. All matmuls bf16 MFMA gemm_bt on a BRICK layout.
// Brick: per 128-row tile, per 32-k slice, element (r,k) at
//   r*32 + ((((k>>3)&3) ^ ((r>>1)&3))<<3) + (k&7)   (granule swizzle baked in).
// GEMM core: NO LDS, NO barriers. Each wave's MFMA fragment is a contiguous
// 1KB global_load_dwordx4 read (lane perm is intra-1KB), streamed straight
// into VGPRs with a 2-deep statically-indexed register double buffer; the
// compiler schedules loads early / waitcnts late; waves run free (m114).
// XCD chunk swizzle with by-fastest order keeps each chunk's working set
// (~one A-panel stripe + all B-panels) L2-resident.
// PV row-sums via ones-operand MFMA. d_out doubles as scratch (Vt | inb).
// ---------------------------------------------------------------------------

typedef __attribute__((ext_vector_type(8))) short short8;   // 8 bf16 = 4 VGPRs
typedef __attribute__((ext_vector_type(4))) float f32x4;

static __device__ __forceinline__ unsigned short f2bf(float f) {
  union { float f; unsigned u; } x; x.f = f;
  unsigned r = x.u + 0x7FFFu + ((x.u >> 16) & 1u);   // round-to-nearest-even
  return (unsigned short)(r >> 16);
}

// brick element offset for element (row r_, k k_) in a brick file of depth Kd
static __device__ __forceinline__ long long brickoff(int r_, int k_, int Kd) {
  return (long long)(r_ >> 7) * ((long long)128 * Kd) +
         (long long)(k_ >> 5) * 4096 +
         (r_ & 127) * 32 +
         (((((k_ >> 3) & 3) ^ ((r_ >> 1) & 3))) << 3) +
         (k_ & 7);
}

// f32 row-major [M][1024] -> bf16 bricks (Kd=1024); two tensors per launch.
__global__ __launch_bounds__(256) void cvt_brick_kernel(
    const float* __restrict__ s0, const float* __restrict__ s1,
    unsigned short* __restrict__ o0, unsigned short* __restrict__ o1,
    long long ngran) {
  const float* src = blockIdx.y ? s1 : s0;
  unsigned short* dst = blockIdx.y ? o1 : o0;
  long long gid = (long long)blockIdx.x * 256 + threadIdx.x;
  const long long stride = (long long)gridDim.x * 256;
  for (; gid < ngran; gid += stride) {
    const int tile = (int)(gid >> 14);          // 16384 granules per 128x1024 tile
    const int g2 = (int)(gid & 16383);
    const int ks = g2 >> 9;                     // k-slice
    const int rp = g2 & 511;
    const int r = rp >> 2;                      // row in tile
    const int p = rp & 3;                       // stored granule position
    const int g = p ^ ((r >> 1) & 3);           // source logical granule
    const float* sp = src + (long long)(tile * 128 + r) * 1024 + ks * 32 + g * 8;
    float4 u0 = ((const float4*)sp)[0];
    float4 u1 = ((const float4*)sp)[1];
    short8 pk;
    pk[0] = (short)f2bf(u0.x); pk[1] = (short)f2bf(u0.y);
    pk[2] = (short)f2bf(u0.z); pk[3] = (short)f2bf(u0.w);
    pk[4] = (short)f2bf(u1.x); pk[5] = (short)f2bf(u1.y);
    pk[6] = (short)f2bf(u1.z); pk[7] = (short)f2bf(u1.w);
    *(short8*)&dst[gid * 8] = pk;
  }
}

// all four C*C weights f32 -> bricks in one launch (blockIdx.y selects)
__global__ __launch_bounds__(256) void wcvt_brick_kernel(
    const float* __restrict__ w0, const float* __restrict__ w1,
    const float* __restrict__ w2, const float* __restrict__ w3,
    unsigned short* __restrict__ o0, unsigned short* __restrict__ o1,
    unsigned short* __restrict__ o2, unsigned short* __restrict__ o3) {
  const float* src; unsigned short* dst;
  switch (blockIdx.y) {
    case 0: src = w0; dst = o0; break;
    case 1: src = w1; dst = o1; break;
    case 2: src = w2; dst = o2; break;
    default: src = w3; dst = o3; break;
  }
  const int gid = blockIdx.x * 256 + threadIdx.x;   // 512 blocks * 256 = 131072 exact
  const int tile = gid >> 14;
  const int g2 = gid & 16383;
  const int ks = g2 >> 9;
  const int rp = g2 & 511;
  const int r = rp >> 2;
  const int p = rp & 3;
  const int g = p ^ ((r >> 1) & 3);
  const float* sp = src + (long long)(tile * 128 + r) * 1024 + ks * 32 + g * 8;
  float4 u0 = ((const float4*)sp)[0];
  float4 u1 = ((const float4*)sp)[1];
  short8 pk;
  pk[0] = (short)f2bf(u0.x); pk[1] = (short)f2bf(u0.y);
  pk[2] = (short)f2bf(u0.z); pk[3] = (short)f2bf(u0.w);
  pk[4] = (short)f2bf(u1.x); pk[5] = (short)f2bf(u1.y);
  pk[6] = (short)f2bf(u1.z); pk[7] = (short)f2bf(u1.w);
  *(short8*)&dst[(long long)gid * 8] = pk;
}

#define EPI_BF16 0        // brick write, Kd = ldd
#define EPI_BF16_TRANS 1  // brick write transposed (Vt), Kd = ldd
#define EPI_EXP 2         // brick write exp(acc), Kd = ldd
#define EPI_PV 3          // brick write acc/rowsum, Kd = ldd
#define EPI_F32 4         // row-major f32, ld = ldd

// D = epilogue(A x B^T (+bias)(*scale)); A,B are BRICK files. No LDS.
// ldaK/ldbK: brick K-depth of A/B. sA/sBflat: flat batch elem offsets.
// sBslice/kOffB: per-z / constant B k-slice offsets. NT: K/32 slices (even).
template <int EPI, bool HAS_BIAS>
__global__ __launch_bounds__(256, 3) void gemm_kernel(
    const unsigned short* __restrict__ A, const unsigned short* __restrict__ B,
    const float* __restrict__ bias, void* __restrict__ Dv,
    int NT, int ldaK, int ldbK, int ldd,
    long long sA, long long sBflat, int sBslice, int kOffB,
    long long sD, float scale) {
  // ---- XCD chunk swizzle, by-fastest order inside each chunk ----
  int i = blockIdx.x + gridDim.x * (blockIdx.y + gridDim.y * blockIdx.z);
  const int nwg = gridDim.x * gridDim.y * gridDim.z;
  int v = (i & 7) * (nwg >> 3) + (i >> 3);
  const int by = v % gridDim.y;
  int u = v / gridDim.y;
  const int bx = u % gridDim.x;
  const int bz = u / gridDim.x;

  const int bm = bx * 128;
  const int bn = by * 128;
  const int tid = threadIdx.x;
  const int lane = tid & 63;
  const int wid = tid >> 6;
  const int wr = (wid >> 1) * 64;
  const int wc = (wid & 1) * 64;
  const int fr = lane & 15;
  const int hi = lane >> 4;
  // per-lane offset inside a fragment's contiguous 1KB block (intra-1KB perm)
  const int laneoff = fr * 32 + ((hi ^ ((fr >> 1) & 3)) << 3);

  f32x4 acc[4][4];
#pragma unroll
  for (int m = 0; m < 4; ++m)
#pragma unroll
    for (int n = 0; n < 4; ++n) acc[m][n] = (f32x4){0.f, 0.f, 0.f, 0.f};

  f32x4 asum[4];
  short8 ones;
#pragma unroll
  for (int m = 0; m < 4; ++m) asum[m] = (f32x4){0.f, 0.f, 0.f, 0.f};
#pragma unroll
  for (int j = 0; j < 8; ++j) ones[j] = (short)0x3F80;  // bf16 1.0

  const unsigned short* Ap = A + bz * sA + (long long)(bm >> 7) * 128 * ldaK +
                             wr * 32 + laneoff;
  const unsigned short* Bp = B + bz * sBflat + (long long)(bn >> 7) * 128 * ldbK +
                             (long long)(kOffB + bz * sBslice) * 4096 +
                             wc * 32 + laneoff;

  // 2-deep register double buffer, all statically indexed (rule #20)
  short8 a0[4], b0[4], a1[4], b1[4];
  auto LDA = [&](short8 (&d)[4], int t) {
    const unsigned short* p = Ap + (long long)t * 4096;
#pragma unroll
    for (int m = 0; m < 4; ++m) d[m] = *(const short8*)(p + m * 512);
  };
  auto LDB = [&](short8 (&d)[4], int t) {
    const unsigned short* p = Bp + (long long)t * 4096;
#pragma unroll
    for (int n = 0; n < 4; ++n) d[n] = *(const short8*)(p + n * 512);
  };
  auto FMA = [&](short8 (&a)[4], short8 (&b)[4]) {
#pragma unroll
    for (int m = 0; m < 4; ++m)
#pragma unroll
      for (int n = 0; n < 4; ++n)
        acc[m][n] = __builtin_amdgcn_mfma_f32_16x16x32_bf16(a[m], b[n],
                                                            acc[m][n], 0, 0, 0);
    if (EPI == EPI_PV) {
#pragma unroll
      for (int m = 0; m < 4; ++m)
        asum[m] = __builtin_amdgcn_mfma_f32_16x16x32_bf16(a[m], ones,
                                                          asum[m], 0, 0, 0);
    }
  };

  LDA(a0, 0); LDB(b0, 0);
  LDA(a1, 1); LDB(b1, 1);
  for (int t = 0; t < NT - 2; t += 2) {
    FMA(a0, b0);
    LDA(a0, t + 2); LDB(b0, t + 2);
    FMA(a1, b1);
    LDA(a1, t + 3); LDB(b1, t + 3);
  }
  FMA(a0, b0);
  FMA(a1, b1);

  // ---- epilogue: C/D frag layout col=lane&15, row=(lane>>4)*4+j ----
  const int cr = hi * 4;
  const int cc = fr;
#pragma unroll
  for (int m = 0; m < 4; ++m) {
    const int row0 = bm + wr + m * 16 + cr;
#pragma unroll
    for (int n = 0; n < 4; ++n) {
      const int col = bn + wc + n * 16 + cc;
      const float bv = HAS_BIAS ? bias[col] : 0.f;
      if (EPI == EPI_F32) {
        float* D = (float*)Dv + bz * sD;
#pragma unroll
        for (int j = 0; j < 4; ++j)
          D[(long long)(row0 + j) * ldd + col] = acc[m][n][j] + bv;
      } else if (EPI == EPI_BF16) {
        unsigned short* D = (unsigned short*)Dv + bz * sD;
#pragma unroll
        for (int j = 0; j < 4; ++j)
          D[brickoff(row0 + j, col, ldd)] = f2bf((acc[m][n][j] + bv) * scale);
      } else if (EPI == EPI_BF16_TRANS) {
        unsigned short* D = (unsigned short*)Dv + bz * sD;
#pragma unroll
        for (int j = 0; j < 4; ++j)
          D[brickoff(col, row0 + j, ldd)] = f2bf((acc[m][n][j] + bv) * scale);
      } else if (EPI == EPI_EXP) {
        unsigned short* D = (unsigned short*)Dv + bz * sD;
#pragma unroll
        for (int j = 0; j < 4; ++j)
          D[brickoff(row0 + j, col, ldd)] = f2bf(__expf(acc[m][n][j]));
      } else {  // EPI_PV
        unsigned short* D = (unsigned short*)Dv + bz * sD;
#pragma unroll
        for (int j = 0; j < 4; ++j) {
          const float li = 1.f / asum[m][j];
          D[brickoff(row0 + j, col, ldd)] = f2bf(acc[m][n][j] * li);
        }
      }
    }
  }
}

extern "C" void kernel_launch(void* const* d_in, const int* in_sizes, int n_in,
                              void* d_out, int out_size, void* d_ws, size_t ws_size,
                              hipStream_t stream) {
  (void)in_sizes; (void)n_in; (void)out_size;
  const float* input  = (const float*)d_in[0];
  const float* memory = (const float*)d_in[1];
  const float* Wq = (const float*)d_in[2];
  const float* bq = (const float*)d_in[3];
  const float* Wk = (const float*)d_in[4];
  const float* bk = (const float*)d_in[5];
  const float* Wv = (const float*)d_in[6];
  const float* bv = (const float*)d_in[7];
  const float* Wo = (const float*)d_in[8];
  const float* bo = (const float*)d_in[9];
  float* out = (float*)d_out;

  const int S = 2048, C = 1024;
  const int CB = 4;
  const long long BS = 16384;
  const long long N_IN = BS * C;        // 16,777,216
  const long long N_W  = (long long)C * C;

  char* p = (char*)d_ws;
  auto alloc = [&](size_t bytes) {
    char* r = p;
    p += (bytes + 255) & ~(size_t)255;
    return r;
  };
  unsigned short* wqb  = (unsigned short*)alloc(N_W * 2);
  unsigned short* wkb  = (unsigned short*)alloc(N_W * 2);
  unsigned short* wvb  = (unsigned short*)alloc(N_W * 2);
  unsigned short* wob  = (unsigned short*)alloc(N_W * 2);
  unsigned short* Qb   = (unsigned short*)alloc(N_IN * 2);   // bricks Kd=1024; later sel
  unsigned short* Kb   = (unsigned short*)alloc(N_IN * 2);   // bricks Kd=1024
  unsigned short* Xb   = (unsigned short*)alloc(N_IN * 2);   // memb bricks, then Pt
  if ((size_t)(p - (char*)d_ws) > ws_size) return;

  unsigned short* Vt  = (unsigned short*)d_out;          // V bricks (rows=c, Kd=16384)
  unsigned short* inb = (unsigned short*)d_out + N_IN;   // input bricks Kd=1024
  unsigned short* memb = Xb;
  unsigned short* Pt   = Xb;                             // P~ bricks Kd=2048 (CB batches)

  // ---- f32 -> bf16 bricks ----
  wcvt_brick_kernel<<<dim3(512, 4, 1), 256, 0, stream>>>(Wq, Wk, Wv, Wo,
                                                         wqb, wkb, wvb, wob);
  cvt_brick_kernel<<<dim3(2048, 2, 1), 256, 0, stream>>>(memory, input, memb, inb,
                                                         N_IN / 8);

  const float depth_scale = 0.03125f;  // 1024^-0.5

  // ---- projections (NT=32): grid (128,8)=1024 blocks ----
  gemm_kernel<EPI_BF16, true><<<dim3(128, 8, 1), 256, 0, stream>>>(
      memb, wkb, bk, Kb, 32, C, C, C, 0, 0, 0, 0, 0, 1.0f);
  gemm_kernel<EPI_BF16_TRANS, true><<<dim3(128, 8, 1), 256, 0, stream>>>(
      memb, wvb, bv, Vt, 32, C, C, (int)BS, 0, 0, 0, 0, 0, 1.0f);
  gemm_kernel<EPI_BF16, true><<<dim3(128, 8, 1), 256, 0, stream>>>(
      inb, wqb, bq, Qb, 32, C, C, C, 0, 0, 0, 0, 0, depth_scale);

  // ---- attention, CB=4 batches per chunk (memb dead -> Pt) ----
  for (int c = 0; c < 8 / CB; ++c) {
    const long long qoff = (long long)c * CB * S * C;
    // P~ = exp(Q[b] @ K[b]^T) -> Pt bricks Kd=2048; grid (16,16,4)=1024
    gemm_kernel<EPI_EXP, false><<<dim3(16, 16, CB), 256, 0, stream>>>(
        Qb + qoff, Kb + qoff, nullptr, Pt,
        32, C, C, S, (long long)S * C, (long long)S * C, 0, 0,
        (long long)S * S, 1.0f);
    // sel[b] = (P~ @ V[b]) / rowsum -> sel bricks over dead Q rows; grid (16,8,4)=512
    gemm_kernel<EPI_PV, false><<<dim3(16, 8, CB), 256, 0, stream>>>(
        Pt, Vt, nullptr, Qb + qoff,
        64, S, (int)BS, C, (long long)S * S, 0, 64, c * CB * 64,
        (long long)S * C, 1.0f);
  }

  // ---- out = sel @ Wo^T + bo -> f32 row-major d_out ----
  gemm_kernel<EPI_F32, true><<<dim3(128, 8, 1), 256, 0, stream>>>(
      Qb, wob, bo, out, 32, C, C, C, 0, 0, 0, 0, 0, 1.0f);
}